// Round 5
// baseline (877.827 us; speedup 1.0000x reference)
//
#include <hip/hip_runtime.h>
#include <hip/hip_fp16.h>

#define HW 16384

typedef __attribute__((ext_vector_type(8))) short short8;
typedef __attribute__((ext_vector_type(4))) float f32x4;

__device__ __forceinline__ unsigned short f2bf(float f) {
    union { float f; unsigned int u; } v; v.f = f;
    unsigned int r = (v.u + 0x7FFFu + ((v.u >> 16) & 1u)) >> 16;
    return (unsigned short)r;
}
__device__ __forceinline__ float bf2f(unsigned short u) {
    union { unsigned int u; float f; } v; v.u = ((unsigned int)u) << 16;
    return v.f;
}

// ---------------------------------------------------------------- sentinel
__global__ void k_sentinel(float* out, float v, int nelem) {
    int i = blockIdx.x * 256 + threadIdx.x;
    if (i < nelem) out[i] = v;
}

// ---------------------------------------------------------------- upsample 64->128, align_corners
__global__ __launch_bounds__(256) void k_upsample(const float* __restrict__ sp,
                                                  float* __restrict__ spu) {
    int idx = blockIdx.x * 256 + threadIdx.x;   // 8*256*128*128
    int x = idx & 127, y = (idx >> 7) & 127;
    int nc = idx >> 14;
    const float* src = sp + (long)nc * 4096;
    float fy = y * (63.0f / 127.0f);
    float fx = x * (63.0f / 127.0f);
    int y0 = (int)fy, x0 = (int)fx;
    float wy = fy - y0, wx = fx - x0;
    int y1 = min(y0 + 1, 63), x1 = min(x0 + 1, 63);
    float v00 = src[y0 * 64 + x0], v01 = src[y0 * 64 + x1];
    float v10 = src[y1 * 64 + x0], v11 = src[y1 * 64 + x1];
    float a = v00 * (1.0f - wy) + v10 * wy;
    float b = v01 * (1.0f - wy) + v11 * wy;
    spu[idx] = a * (1.0f - wx) + b * wx;
}

// ---------------------------------------------------------------- MFMA GEMM: Y[c][p], M=128, K=256
template <int SRCBF>
__global__ __launch_bounds__(256) void k_mgemm(
    const void* __restrict__ Xa_, const void* __restrict__ Xb_,
    long bsA, long bsB,
    const float* __restrict__ Wm,
    const float* __restrict__ gamma,   // null -> no BN scale
    const float* __restrict__ bias,
    unsigned short* __restrict__ Y, int relu) {
    __shared__ short Al[16 * 128 * 8];        // 32 KB: [(kc2*4+quad)*128 + c] chunks of 8 bf16
    __shared__ unsigned short B1[32 * 136];   // 8.5 KB: [k 0..31][p 0..127], row pad 136
    int t = threadIdx.x;
    int lane = t & 63, wv = t >> 6;
    int l15 = lane & 15, quad = lane >> 4;
    int bid = blockIdx.x;                     // 1024 = 8 n * 128 pixel-tiles
    int n = bid >> 7;
    int p0 = (bid & 127) * 128;

    f32x4 acc[8][2];
#pragma unroll
    for (int mt = 0; mt < 8; ++mt)
#pragma unroll
        for (int nt = 0; nt < 2; ++nt) acc[mt][nt] = (f32x4){0.f, 0.f, 0.f, 0.f};

    for (int phase = 0; phase < 2; ++phase) {
        // ---- stage A half (128 channels x 128 k) into fragment-ordered LDS
#pragma unroll
        for (int i = 0; i < 8; ++i) {
            int cid = i * 256 + t;            // 2048 chunks of 8
            int c = cid >> 4, rem = cid & 15;
            int kc2l = rem >> 2, q = rem & 3;
            const float* wp = Wm + (long)c * 256 + phase * 128 + kc2l * 32 + q * 8;
            float4 w0 = *(const float4*)wp;
            float4 w1 = *(const float4*)(wp + 4);
            short8 sv;
            sv[0] = (short)f2bf(w0.x); sv[1] = (short)f2bf(w0.y);
            sv[2] = (short)f2bf(w0.z); sv[3] = (short)f2bf(w0.w);
            sv[4] = (short)f2bf(w1.x); sv[5] = (short)f2bf(w1.y);
            sv[6] = (short)f2bf(w1.z); sv[7] = (short)f2bf(w1.w);
            *(short8*)&Al[((kc2l * 4 + q) * 128 + c) * 8] = sv;
        }
        for (int kc2 = 0; kc2 < 4; ++kc2) {
            // ---- stage B tile (32 k x 128 p) to bf16 LDS
            if (SRCBF) {
                const unsigned short* X = ((const unsigned short*)(phase ? Xb_ : Xa_)) +
                                          (long)n * (phase ? bsB : bsA);
#pragma unroll
                for (int i = 0; i < 2; ++i) {
                    int cid = i * 256 + t;
                    int kl = cid >> 4, c16 = cid & 15;
                    const unsigned short* src = X + (long)(kc2 * 32 + kl) * HW + p0 + c16 * 8;
                    *(uint4*)&B1[kl * 136 + c16 * 8] = *(const uint4*)src;
                }
            } else {
                const float* X = ((const float*)(phase ? Xb_ : Xa_)) +
                                 (long)n * (phase ? bsB : bsA);
#pragma unroll
                for (int i = 0; i < 4; ++i) {
                    int cid = i * 256 + t;
                    int kl = cid >> 5, c8 = cid & 31;
                    const float* src = X + (long)(kc2 * 32 + kl) * HW + p0 + c8 * 4;
                    float4 v = *(const float4*)src;
                    ushort4 s;
                    s.x = f2bf(v.x); s.y = f2bf(v.y); s.z = f2bf(v.z); s.w = f2bf(v.w);
                    *(ushort4*)&B1[kl * 136 + c8 * 4] = s;
                }
            }
            __syncthreads();
            // ---- fragments + MFMA
            short8 af[8];
#pragma unroll
            for (int mt = 0; mt < 8; ++mt)
                af[mt] = *(const short8*)&Al[((kc2 * 4 + quad) * 128 + mt * 16 + l15) * 8];
#pragma unroll
            for (int nt = 0; nt < 2; ++nt) {
                int pl = wv * 32 + nt * 16 + l15;
                short8 bfr;
#pragma unroll
                for (int j = 0; j < 8; ++j)
                    bfr[j] = (short)B1[(quad * 8 + j) * 136 + pl];
#pragma unroll
                for (int mt = 0; mt < 8; ++mt)
                    acc[mt][nt] = __builtin_amdgcn_mfma_f32_16x16x32_bf16(
                        af[mt], bfr, acc[mt][nt], 0, 0, 0);
            }
            __syncthreads();
        }
    }
    // ---- epilogue: D row = channel = mt*16 + quad*4 + reg; col = pixel = l15
    const float inv = 0.99999500003749969f;   // 1/sqrt(1+1e-5)
#pragma unroll
    for (int mt = 0; mt < 8; ++mt) {
#pragma unroll
        for (int reg = 0; reg < 4; ++reg) {
            int c = mt * 16 + quad * 4 + reg;
            float s = gamma ? gamma[c] * inv : 1.0f;
            float bb = bias[c];
#pragma unroll
            for (int nt = 0; nt < 2; ++nt) {
                float v = acc[mt][nt][reg] * s + bb;
                if (relu) v = fmaxf(v, 0.0f);
                Y[((long)n * 128 + c) * HW + p0 + wv * 32 + nt * 16 + l15] = f2bf(v);
            }
        }
    }
}

// ---------------------------------------------------------------- grouped cosine similarity (bf16 in)
__global__ __launch_bounds__(256) void k_sim(const unsigned short* __restrict__ cp1,
                                             const unsigned short* __restrict__ sp1,
                                             float* __restrict__ sim) {
    int idx = blockIdx.x * 256 + threadIdx.x;  // 64 * 16384
    int p = idx & 16383;
    int ng = idx >> 14;
    const unsigned short* a = cp1 + (long)ng * 16 * HW + p;
    const unsigned short* b = sp1 + (long)ng * 16 * HW + p;
    float num = 0, na = 0, nb = 0;
#pragma unroll
    for (int j = 0; j < 16; ++j) {
        float av = bf2f(a[(long)j * HW]), bv = bf2f(b[(long)j * HW]);
        num = fmaf(av, bv, num);
        na = fmaf(av, av, na);
        nb = fmaf(bv, bv, nb);
    }
    na = sqrtf(na); nb = sqrtf(nb);
    sim[idx] = num / (fmaxf(na, 1e-8f) * fmaxf(nb, 1e-8f));
}

// ---------------------------------------------------------------- fdir: 3x3 conv 8->32, pad 1
__global__ __launch_bounds__(256) void k_fdir(const float* __restrict__ sim,
                                              const float* __restrict__ w_dir,
                                              const float* __restrict__ b_dir,
                                              float* __restrict__ fdir) {
    __shared__ float ls[8][18][19];
    __shared__ float lw[8 * 9 * 32];
    int t = threadIdx.x;
    int bid = blockIdx.x;     // 8 * 64
    int n = bid >> 6;
    int tile = bid & 63;
    int ty0 = (tile >> 3) * 16, tx0 = (tile & 7) * 16;
    for (int e = t; e < 2304; e += 256) {
        int co = e & 31; int rem = e >> 5; int tap = rem % 9; int ci = rem / 9;
        lw[ci * 288 + tap * 32 + co] = w_dir[co * 72 + ci * 9 + tap];
    }
    for (int e = t; e < 8 * 18 * 18; e += 256) {
        int ci = e / 324; int rem = e - ci * 324; int yy = rem / 18; int xx = rem - yy * 18;
        int gy = ty0 + yy - 1, gx = tx0 + xx - 1;
        float v = 0.0f;
        if (gy >= 0 && gy < 128 && gx >= 0 && gx < 128)
            v = sim[((long)n * 8 + ci) * HW + gy * 128 + gx];
        ls[ci][yy][xx] = v;
    }
    __syncthreads();
    int yy = t >> 4, xx = t & 15;
    float acc[32] = {};
#pragma unroll
    for (int ci = 0; ci < 8; ++ci)
#pragma unroll
        for (int dy = 0; dy < 3; ++dy)
#pragma unroll
            for (int dx = 0; dx < 3; ++dx) {
                float v = ls[ci][yy + dy][xx + dx];
                const float* wp = &lw[ci * 288 + (dy * 3 + dx) * 32];
#pragma unroll
                for (int o = 0; o < 32; o += 4) {
                    float4 w = *(const float4*)&wp[o];
                    acc[o]     = fmaf(v, w.x, acc[o]);
                    acc[o + 1] = fmaf(v, w.y, acc[o + 1]);
                    acc[o + 2] = fmaf(v, w.z, acc[o + 2]);
                    acc[o + 3] = fmaf(v, w.w, acc[o + 3]);
                }
            }
    long obase = (long)n * 32 * HW + (ty0 + yy) * 128 + tx0 + xx;
    for (int o = 0; o < 32; ++o)
        fdir[obase + (long)o * HW] = acc[o] + b_dir[o];
}

// ---------------------------------------------------------------- fdist weight prep: fragment-ordered bf16
__global__ __launch_bounds__(256) void k_wprep(const float* __restrict__ w,
                                               unsigned short* __restrict__ wf) {
    int t = blockIdx.x * 256 + threadIdx.x;   // 4608 total
    if (t >= 4608) return;
    int lane = t & 63;
    int mt = (t >> 6) & 1;
    int tap = (t >> 7) % 9;
    int c = t / 1152;
    int o = mt * 16 + (lane & 15);
    int cib = c * 32 + (lane >> 4) * 8;
    short8 sv;
#pragma unroll
    for (int j = 0; j < 8; ++j)
        sv[j] = (short)f2bf(w[(long)o * 1152 + (cib + j) * 9 + tap]);
    *(short8*)&wf[(long)t * 8] = sv;
}

// ---------------------------------------------------------------- fdist: 3x3 conv |cp1-sp1| 128->32 via MFMA
__global__ __launch_bounds__(512) void k_fdist(const unsigned short* __restrict__ cp1,
                                               const unsigned short* __restrict__ sp1,
                                               const unsigned short* __restrict__ wf,
                                               const float* __restrict__ b_dist,
                                               float* __restrict__ fdb) {
    __shared__ unsigned short Bs[32 * 912];   // 58,368 B
    int t = threadIdx.x;
    int lane = t & 63, wv = t >> 6;
    int l15 = lane & 15, quad = lane >> 4;
    int bid = blockIdx.x;
    int n = bid >> 5;
    int row0 = (bid & 31) * 4;

    // zero x-halo columns (cols 7 and 136 of each (kp,row) plane) -- stay zero all chunks
    for (int e = t; e < 384; e += 512) {
        int kp = e / 12, rem = e % 12, row = rem >> 1;
        Bs[kp * 912 + row * 144 + ((rem & 1) ? 136 : 7)] = 0;
    }

    f32x4 acc[2][4];
#pragma unroll
    for (int mt = 0; mt < 2; ++mt)
#pragma unroll
        for (int nt = 0; nt < 4; ++nt) acc[mt][nt] = (f32x4){0.f, 0.f, 0.f, 0.f};

    for (int c = 0; c < 4; ++c) {
        if (c) __syncthreads();            // previous compute done reading Bs
        // ---- stage |cp1-sp1| chunk (32 ch x 6 rows x 128 x) as bf16
#pragma unroll
        for (int i = 0; i < 6; ++i) {
            int e = i * 512 + t;           // 3072 units of 8 x-pixels
            int k = e / 96;
            int rem = e - k * 96;
            int row = rem >> 4, col8 = rem & 15;
            int gy = row0 + row - 1;
            short8 dv = (short8){0, 0, 0, 0, 0, 0, 0, 0};
            if (gy >= 0 && gy < 128) {
                long gidx = ((long)(n * 128 + c * 32 + k)) * HW + gy * 128 + col8 * 8;
                short8 a = *(const short8*)(cp1 + gidx);
                short8 b = *(const short8*)(sp1 + gidx);
#pragma unroll
                for (int j = 0; j < 8; ++j)
                    dv[j] = (short)f2bf(fabsf(bf2f((unsigned short)a[j]) -
                                              bf2f((unsigned short)b[j])));
            }
            *(short8*)&Bs[((k & 7) * 4 + (k >> 3)) * 912 + row * 144 + 8 + col8 * 8] = dv;
        }
        __syncthreads();
        // ---- A fragments for this chunk: 9 taps x 2 mt, single b128 global load each (L2-hot)
        short8 af[9][2];
        const short8* wp = ((const short8*)wf) + (long)c * 1152 + lane;
#pragma unroll
        for (int tap = 0; tap < 9; ++tap)
#pragma unroll
            for (int mt = 0; mt < 2; ++mt)
                af[tap][mt] = wp[(tap * 2 + mt) * 64];
        // ---- MFMA over 9 taps
#pragma unroll
        for (int tap = 0; tap < 9; ++tap) {
            int dy = tap / 3, dx = tap % 3;
#pragma unroll
            for (int nt = 0; nt < 4; ++nt) {
                int tp = wv * 64 + nt * 16 + l15;
                int ba = quad * 912 + ((tp >> 7) + dy) * 144 + (tp & 127) + dx + 7;
                short8 bfr;
#pragma unroll
                for (int j = 0; j < 8; ++j)
                    bfr[j] = (short)Bs[ba + j * 3648];   // j*4 planes * 912
                acc[0][nt] = __builtin_amdgcn_mfma_f32_16x16x32_bf16(
                    af[tap][0], bfr, acc[0][nt], 0, 0, 0);
                acc[1][nt] = __builtin_amdgcn_mfma_f32_16x16x32_bf16(
                    af[tap][1], bfr, acc[1][nt], 0, 0, 0);
            }
        }
    }
    // ---- epilogue: c_out = mt*16 + quad*4 + reg; pixel = wv*64 + nt*16 + l15
#pragma unroll
    for (int mt = 0; mt < 2; ++mt)
#pragma unroll
        for (int reg = 0; reg < 4; ++reg) {
            int co = mt * 16 + quad * 4 + reg;
            float bb = b_dist[co];
            long ob = ((long)n * 32 + co) * HW + row0 * 128;
#pragma unroll
            for (int nt = 0; nt < 4; ++nt) {
                int tp = wv * 64 + nt * 16 + l15;
                fdb[ob + tp] = acc[mt][nt][reg] + bb;
            }
        }
}

// ---------------------------------------------------------------- off: 1x1 conv 192->32
__global__ __launch_bounds__(256) void k_off(const unsigned short* __restrict__ redim,
                                             const float* __restrict__ fdir,
                                             const float* __restrict__ fdb,
                                             const float* __restrict__ w_off,
                                             const float* __restrict__ b_off,
                                             float* __restrict__ off) {
    __shared__ float lw[192 * 32];
    int t = threadIdx.x;
    int bid = blockIdx.x;    // 8 * 64
    int n = bid >> 6;
    int p0 = (bid & 63) * 256;
    for (int e = t; e < 6144; e += 256) {
        int co = e & 31; int k = e >> 5;
        lw[k * 32 + co] = w_off[co * 192 + k];
    }
    __syncthreads();
    int p = p0 + t;
    float acc[32] = {};
    for (int k = 0; k < 192; ++k) {
        float v;
        if (k < 128)      v = bf2f(redim[((long)n * 128 + k) * HW + p]);
        else if (k < 160) v = fdir[((long)n * 32 + (k - 128)) * HW + p];
        else              v = fdb[((long)n * 32 + (k - 160)) * HW + p];
        const float* wp = &lw[k * 32];
#pragma unroll
        for (int o = 0; o < 32; o += 4) {
            float4 w = *(const float4*)&wp[o];
            acc[o]     = fmaf(v, w.x, acc[o]);
            acc[o + 1] = fmaf(v, w.y, acc[o + 1]);
            acc[o + 2] = fmaf(v, w.z, acc[o + 2]);
            acc[o + 3] = fmaf(v, w.w, acc[o + 3]);
        }
    }
    for (int o = 0; o < 32; ++o)
        off[((long)n * 32 + o) * HW + p] = acc[o] + b_off[o];
}

// ---------------------------------------------------------------- gsample metadata prep
// per (n,gg,pixel): packed corner offsets + fp16 weight factors for both samples.
// o00|dx<<14|dy<<15 (u16); factors a=(1-wx)vx0, b=wx*vx1, c=(1-wy)vy0, d=wy*vy1
// so w00=a*c, w01=b*c, w10=a*d, w11=b*d (validity folded in).
__device__ __forceinline__ void gs_meta(float gx, float gy,
                                        unsigned int& pk, unsigned int& hab,
                                        unsigned int& hcd) {
    float x0f = floorf(gx), y0f = floorf(gy);
    float wx = gx - x0f, wy = gy - y0f;
    int x0 = (int)x0f, y0 = (int)y0f;
    float vx0 = (x0 >= 0 && x0 <= 127) ? 1.f : 0.f;
    float vx1 = (x0 + 1 >= 0 && x0 + 1 <= 127) ? 1.f : 0.f;
    float vy0 = (y0 >= 0 && y0 <= 127) ? 1.f : 0.f;
    float vy1 = (y0 + 1 >= 0 && y0 + 1 <= 127) ? 1.f : 0.f;
    int x0c = min(max(x0, 0), 127), x1c = min(max(x0 + 1, 0), 127);
    int y0c = min(max(y0, 0), 127), y1c = min(max(y0 + 1, 0), 127);
    unsigned int o00 = (unsigned int)(y0c * 128 + x0c);
    unsigned int dx = (unsigned int)(x1c - x0c), dy = (unsigned int)(y1c - y0c);
    pk = o00 | (dx << 14) | (dy << 15);
    __half2 ab = __floats2half2_rn((1.f - wx) * vx0, wx * vx1);
    __half2 cd = __floats2half2_rn((1.f - wy) * vy0, wy * vy1);
    hab = *(unsigned int*)&ab;
    hcd = *(unsigned int*)&cd;
}

__global__ __launch_bounds__(256) void k_gprep(const float* __restrict__ off,
                                               unsigned int* __restrict__ pofs,
                                               uint4* __restrict__ phw) {
    int idx = blockIdx.x * 256 + threadIdx.x;  // 64 * 16384
    int p = idx & 16383;
    int ng = idx >> 14;
    int n = ng >> 3, gg = ng & 7;
    int x = p & 127, y = p >> 7;
    const float* ob = off + (long)n * 32 * HW + p;
    float lx = ob[(long)(2 * gg) * HW];
    float ly = ob[(long)(2 * gg + 1) * HW];
    float hx = ob[(long)(16 + 2 * gg) * HW];
    float hy = ob[(long)(17 + 2 * gg) * HW];
    const float C = 127.0f / 256.0f;
    unsigned int pkc, cab, ccd, pks, sab, scd;
    gs_meta((float)x + lx * C, (float)y + ly * C, pkc, cab, ccd);
    gs_meta((float)x + hx * C, (float)y + hy * C, pks, sab, scd);
    pofs[idx] = pkc | (pks << 16);
    phw[idx] = make_uint4(cab, ccd, sab, scd);
}

// ---------------------------------------------------------------- grid sample + add
// bf16 LDS planes (32 KB each) -> 64 KB/block -> 2 blocks/CU so staging of one
// block overlaps gathering of the other (round-4 profile showed 1-block/CU
// serial stage->gather at 114 us with HBM 30% / VALU 35% / DS all unsaturated).
__device__ __forceinline__ float2 h2f2(unsigned int u) {
    __half2 h = *(__half2*)&u;
    return __half22float2(h);
}

__global__ __launch_bounds__(1024) void k_gsample(const float* __restrict__ cp,
                                                  const float* __restrict__ spu,
                                                  const unsigned int* __restrict__ pofs,
                                                  const uint4* __restrict__ phw,
                                                  float* __restrict__ out) {
    __shared__ unsigned short lc[16384];   // cp plane bf16 (32 KB)
    __shared__ unsigned short lsp[16384];  // spu plane bf16 (32 KB)
    int t = threadIdx.x;
    // XCD-aware bijective swizzle: 2048 blocks = 8 XCD * 256; blocks sharing
    // (n,gg) land on the same XCD -> prep slice stays L2-resident.
    int bid = (blockIdx.x & 7) * 256 + (blockIdx.x >> 3);
    int n = bid >> 8;
    int gg = (bid >> 5) & 7;
    int ci = bid & 31;
    long plane = ((long)n * 256 + gg * 32 + ci) * (long)HW;
    const float* pc = cp + plane;
    const float* ps = spu + plane;
    // ---- stage both planes as bf16 (fp32 global reads unchanged)
#pragma unroll
    for (int i = 0; i < 4; ++i) {
        int idx = (i * 1024 + t) * 4;
        float4 a = *(const float4*)&pc[idx];
        float4 b = *(const float4*)&ps[idx];
        ushort4 ua, ub;
        ua.x = f2bf(a.x); ua.y = f2bf(a.y); ua.z = f2bf(a.z); ua.w = f2bf(a.w);
        ub.x = f2bf(b.x); ub.y = f2bf(b.y); ub.z = f2bf(b.z); ub.w = f2bf(b.w);
        *(ushort4*)&lc[idx] = ua;
        *(ushort4*)&lsp[idx] = ub;
    }
    // ---- prefetch packed offsets (independent of LDS; in flight over the barrier)
    long base = ((long)n * 8 + gg) * (long)HW;
    unsigned int pks[16];
#pragma unroll
    for (int it = 0; it < 16; ++it) pks[it] = pofs[base + it * 1024 + t];
    __syncthreads();
    // ---- gather from LDS, 16 pixels/thread
    float* op = out + plane;
#pragma unroll
    for (int it = 0; it < 16; ++it) {
        int p = it * 1024 + t;
        unsigned int pk = pks[it];
        uint4 hw = phw[base + p];
        // cs
        unsigned int oc = pk & 0x3FFFu;
        unsigned int dxc = (pk >> 14) & 1u, dyc = (pk >> 15) & 1u;
        float2 ab = h2f2(hw.x), cd = h2f2(hw.y);
        unsigned int oc1 = oc + (dyc << 7);
        float r = bf2f(lc[oc]) * (ab.x * cd.x) + bf2f(lc[oc + dxc]) * (ab.y * cd.x) +
                  bf2f(lc[oc1]) * (ab.x * cd.y) + bf2f(lc[oc1 + dxc]) * (ab.y * cd.y);
        // ss
        unsigned int os = (pk >> 16) & 0x3FFFu;
        unsigned int dxs = (pk >> 30) & 1u, dys = pk >> 31;
        float2 ab2 = h2f2(hw.z), cd2 = h2f2(hw.w);
        unsigned int os1 = os + (dys << 7);
        r += bf2f(lsp[os]) * (ab2.x * cd2.x) + bf2f(lsp[os + dxs]) * (ab2.y * cd2.x) +
             bf2f(lsp[os1]) * (ab2.x * cd2.y) + bf2f(lsp[os1 + dxs]) * (ab2.y * cd2.y);
        op[p] = r;
    }
}

// ---------------------------------------------------------------- launch
extern "C" void kernel_launch(void* const* d_in, const int* in_sizes, int n_in,
                              void* d_out, int out_size, void* d_ws, size_t ws_size,
                              hipStream_t stream) {
    const float* cp      = (const float*)d_in[0];
    const float* sp      = (const float*)d_in[1];
    const float* w_cp    = (const float*)d_in[2];
    const float* g_cp    = (const float*)d_in[3];
    const float* b_cp    = (const float*)d_in[4];
    const float* w_sp    = (const float*)d_in[5];
    const float* g_sp    = (const float*)d_in[6];
    const float* b_sp    = (const float*)d_in[7];
    const float* w_redim = (const float*)d_in[8];
    const float* b_redim = (const float*)d_in[9];
    const float* w_dir   = (const float*)d_in[10];
    const float* b_dir   = (const float*)d_in[11];
    const float* w_dist  = (const float*)d_in[12];
    const float* b_dist  = (const float*)d_in[13];
    const float* w_off   = (const float*)d_in[14];
    const float* b_off   = (const float*)d_in[15];
    float* out = (float*)d_out;

    char* ws = (char*)d_ws;
    size_t o = 0;
    float* spu            = (float*)(ws + o);          o += 8L * 256 * HW * 4;   // 134 MB
    unsigned short* cp1b  = (unsigned short*)(ws + o); o += 8L * 128 * HW * 2;   // 33.5 MB
    unsigned short* sp1b  = (unsigned short*)(ws + o); o += 8L * 128 * HW * 2;
    unsigned short* redb  = (unsigned short*)(ws + o); o += 8L * 128 * HW * 2;
    float* simb           = (float*)(ws + o);          o += 8L * 8 * HW * 4;
    float* fdirb          = (float*)(ws + o);          o += 8L * 32 * HW * 4;
    float* fdb            = (float*)(ws + o);          o += 8L * 32 * HW * 4;    // single full-K buffer
    float* offb           = (float*)(ws + o);          o += 8L * 32 * HW * 4;
    unsigned short* wfb   = (unsigned short*)(ws + o); o += 4608L * 8 * 2;       // 73,728 B
    unsigned int* pofsb   = (unsigned int*)(ws + o);   o += 64L * HW * 4;        // 4.2 MB
    uint4* phwb           = (uint4*)(ws + o);          o += 64L * HW * 16;       // 16.8 MB

    if (ws_size < o) {
        k_sentinel<<<(out_size + 255) / 256, 256, 0, stream>>>(
            out, (float)(ws_size >> 20), out_size);
        return;
    }

    k_upsample<<<131072, 256, 0, stream>>>(sp, spu);
    k_wprep<<<18, 256, 0, stream>>>(w_dist, wfb);
    k_mgemm<0><<<1024, 256, 0, stream>>>(cp, cp + 128L * HW, 256L * HW, 256L * HW,
                                         w_cp, g_cp, b_cp, cp1b, 1);
    k_mgemm<0><<<1024, 256, 0, stream>>>(spu, spu + 128L * HW, 256L * HW, 256L * HW,
                                         w_sp, g_sp, b_sp, sp1b, 1);
    k_mgemm<1><<<1024, 256, 0, stream>>>(cp1b, sp1b, 128L * HW, 128L * HW,
                                         w_redim, nullptr, b_redim, redb, 0);
    k_sim<<<4096, 256, 0, stream>>>(cp1b, sp1b, simb);
    k_fdir<<<512, 256, 0, stream>>>(simb, w_dir, b_dir, fdirb);
    k_fdist<<<256, 512, 0, stream>>>(cp1b, sp1b, wfb, b_dist, fdb);
    k_off<<<512, 256, 0, stream>>>(redb, fdirb, fdb, w_off, b_off, offb);
    k_gprep<<<4096, 256, 0, stream>>>(offb, pofsb, phwb);
    k_gsample<<<2048, 1024, 0, stream>>>(cp, spu, pofsb, phwb, out);
}

// Round 6
// 705.192 us; speedup vs baseline: 1.2448x; 1.2448x over previous
//
#include <hip/hip_runtime.h>
#include <hip/hip_fp16.h>

#define HW 16384

typedef __attribute__((ext_vector_type(8))) short short8;
typedef __attribute__((ext_vector_type(4))) float f32x4;

__device__ __forceinline__ unsigned short f2bf(float f) {
    union { float f; unsigned int u; } v; v.f = f;
    unsigned int r = (v.u + 0x7FFFu + ((v.u >> 16) & 1u)) >> 16;
    return (unsigned short)r;
}
__device__ __forceinline__ float bf2f(unsigned short u) {
    union { unsigned int u; float f; } v; v.u = ((unsigned int)u) << 16;
    return v.f;
}

// ---------------------------------------------------------------- sentinel
__global__ void k_sentinel(float* out, float v, int nelem) {
    int i = blockIdx.x * 256 + threadIdx.x;
    if (i < nelem) out[i] = v;
}

// ---------------------------------------------------------------- upsample 64->128, align_corners, bf16 out
// 2 adjacent x-pixels per thread -> packed u32 stores.
__global__ __launch_bounds__(256) void k_upsample(const float* __restrict__ sp,
                                                  unsigned short* __restrict__ spu) {
    int gid = blockIdx.x * 256 + threadIdx.x;   // 65536 blocks, 2 px/thread
    int p2 = gid * 2;
    int x = p2 & 127, y = (p2 >> 7) & 127;
    int nc = p2 >> 14;
    const float* src = sp + (long)nc * 4096;
    float fy = y * (63.0f / 127.0f);
    int y0 = (int)fy;
    float wy = fy - y0;
    int y1 = min(y0 + 1, 63);
    unsigned int pack = 0;
#pragma unroll
    for (int j = 0; j < 2; ++j) {
        float fx = (x + j) * (63.0f / 127.0f);
        int x0 = (int)fx;
        float wx = fx - x0;
        int x1 = min(x0 + 1, 63);
        float v00 = src[y0 * 64 + x0], v01 = src[y0 * 64 + x1];
        float v10 = src[y1 * 64 + x0], v11 = src[y1 * 64 + x1];
        float a = v00 * (1.0f - wy) + v10 * wy;
        float b = v01 * (1.0f - wy) + v11 * wy;
        float r = a * (1.0f - wx) + b * wx;
        pack |= (unsigned int)f2bf(r) << (16 * j);
    }
    *(unsigned int*)&spu[p2] = pack;
}

// ---------------------------------------------------------------- MFMA GEMM: Y[c][p], M=128, K=256
template <int SRCBF>
__global__ __launch_bounds__(256) void k_mgemm(
    const void* __restrict__ Xa_, const void* __restrict__ Xb_,
    long bsA, long bsB,
    const float* __restrict__ Wm,
    const float* __restrict__ gamma,   // null -> no BN scale
    const float* __restrict__ bias,
    unsigned short* __restrict__ Y, int relu) {
    __shared__ short Al[16 * 128 * 8];        // 32 KB: [(kc2*4+quad)*128 + c] chunks of 8 bf16
    __shared__ unsigned short B1[32 * 136];   // 8.5 KB: [k 0..31][p 0..127], row pad 136
    int t = threadIdx.x;
    int lane = t & 63, wv = t >> 6;
    int l15 = lane & 15, quad = lane >> 4;
    int bid = blockIdx.x;                     // 1024 = 8 n * 128 pixel-tiles
    int n = bid >> 7;
    int p0 = (bid & 127) * 128;

    f32x4 acc[8][2];
#pragma unroll
    for (int mt = 0; mt < 8; ++mt)
#pragma unroll
        for (int nt = 0; nt < 2; ++nt) acc[mt][nt] = (f32x4){0.f, 0.f, 0.f, 0.f};

    for (int phase = 0; phase < 2; ++phase) {
        // ---- stage A half (128 channels x 128 k) into fragment-ordered LDS
#pragma unroll
        for (int i = 0; i < 8; ++i) {
            int cid = i * 256 + t;            // 2048 chunks of 8
            int c = cid >> 4, rem = cid & 15;
            int kc2l = rem >> 2, q = rem & 3;
            const float* wp = Wm + (long)c * 256 + phase * 128 + kc2l * 32 + q * 8;
            float4 w0 = *(const float4*)wp;
            float4 w1 = *(const float4*)(wp + 4);
            short8 sv;
            sv[0] = (short)f2bf(w0.x); sv[1] = (short)f2bf(w0.y);
            sv[2] = (short)f2bf(w0.z); sv[3] = (short)f2bf(w0.w);
            sv[4] = (short)f2bf(w1.x); sv[5] = (short)f2bf(w1.y);
            sv[6] = (short)f2bf(w1.z); sv[7] = (short)f2bf(w1.w);
            *(short8*)&Al[((kc2l * 4 + q) * 128 + c) * 8] = sv;
        }
        for (int kc2 = 0; kc2 < 4; ++kc2) {
            // ---- stage B tile (32 k x 128 p) to bf16 LDS
            if (SRCBF) {
                const unsigned short* X = ((const unsigned short*)(phase ? Xb_ : Xa_)) +
                                          (long)n * (phase ? bsB : bsA);
#pragma unroll
                for (int i = 0; i < 2; ++i) {
                    int cid = i * 256 + t;
                    int kl = cid >> 4, c16 = cid & 15;
                    const unsigned short* src = X + (long)(kc2 * 32 + kl) * HW + p0 + c16 * 8;
                    *(uint4*)&B1[kl * 136 + c16 * 8] = *(const uint4*)src;
                }
            } else {
                const float* X = ((const float*)(phase ? Xb_ : Xa_)) +
                                 (long)n * (phase ? bsB : bsA);
#pragma unroll
                for (int i = 0; i < 4; ++i) {
                    int cid = i * 256 + t;
                    int kl = cid >> 5, c8 = cid & 31;
                    const float* src = X + (long)(kc2 * 32 + kl) * HW + p0 + c8 * 4;
                    float4 v = *(const float4*)src;
                    ushort4 s;
                    s.x = f2bf(v.x); s.y = f2bf(v.y); s.z = f2bf(v.z); s.w = f2bf(v.w);
                    *(ushort4*)&B1[kl * 136 + c8 * 4] = s;
                }
            }
            __syncthreads();
            // ---- fragments + MFMA
            short8 af[8];
#pragma unroll
            for (int mt = 0; mt < 8; ++mt)
                af[mt] = *(const short8*)&Al[((kc2 * 4 + quad) * 128 + mt * 16 + l15) * 8];
#pragma unroll
            for (int nt = 0; nt < 2; ++nt) {
                int pl = wv * 32 + nt * 16 + l15;
                short8 bfr;
#pragma unroll
                for (int j = 0; j < 8; ++j)
                    bfr[j] = (short)B1[(quad * 8 + j) * 136 + pl];
#pragma unroll
                for (int mt = 0; mt < 8; ++mt)
                    acc[mt][nt] = __builtin_amdgcn_mfma_f32_16x16x32_bf16(
                        af[mt], bfr, acc[mt][nt], 0, 0, 0);
            }
            __syncthreads();
        }
    }
    // ---- epilogue: D row = channel = mt*16 + quad*4 + reg; col = pixel = l15
    const float inv = 0.99999500003749969f;   // 1/sqrt(1+1e-5)
#pragma unroll
    for (int mt = 0; mt < 8; ++mt) {
#pragma unroll
        for (int reg = 0; reg < 4; ++reg) {
            int c = mt * 16 + quad * 4 + reg;
            float s = gamma ? gamma[c] * inv : 1.0f;
            float bb = bias[c];
#pragma unroll
            for (int nt = 0; nt < 2; ++nt) {
                float v = acc[mt][nt][reg] * s + bb;
                if (relu) v = fmaxf(v, 0.0f);
                Y[((long)n * 128 + c) * HW + p0 + wv * 32 + nt * 16 + l15] = f2bf(v);
            }
        }
    }
}

// ---------------------------------------------------------------- grouped cosine similarity (bf16 in)
__global__ __launch_bounds__(256) void k_sim(const unsigned short* __restrict__ cp1,
                                             const unsigned short* __restrict__ sp1,
                                             float* __restrict__ sim) {
    int idx = blockIdx.x * 256 + threadIdx.x;  // 64 * 16384
    int p = idx & 16383;
    int ng = idx >> 14;
    const unsigned short* a = cp1 + (long)ng * 16 * HW + p;
    const unsigned short* b = sp1 + (long)ng * 16 * HW + p;
    float num = 0, na = 0, nb = 0;
#pragma unroll
    for (int j = 0; j < 16; ++j) {
        float av = bf2f(a[(long)j * HW]), bv = bf2f(b[(long)j * HW]);
        num = fmaf(av, bv, num);
        na = fmaf(av, av, na);
        nb = fmaf(bv, bv, nb);
    }
    na = sqrtf(na); nb = sqrtf(nb);
    sim[idx] = num / (fmaxf(na, 1e-8f) * fmaxf(nb, 1e-8f));
}

// ---------------------------------------------------------------- fdir: 3x3 conv 8->32, pad 1
__global__ __launch_bounds__(256) void k_fdir(const float* __restrict__ sim,
                                              const float* __restrict__ w_dir,
                                              const float* __restrict__ b_dir,
                                              float* __restrict__ fdir) {
    __shared__ float ls[8][18][19];
    __shared__ float lw[8 * 9 * 32];
    int t = threadIdx.x;
    int bid = blockIdx.x;     // 8 * 64
    int n = bid >> 6;
    int tile = bid & 63;
    int ty0 = (tile >> 3) * 16, tx0 = (tile & 7) * 16;
    for (int e = t; e < 2304; e += 256) {
        int co = e & 31; int rem = e >> 5; int tap = rem % 9; int ci = rem / 9;
        lw[ci * 288 + tap * 32 + co] = w_dir[co * 72 + ci * 9 + tap];
    }
    for (int e = t; e < 8 * 18 * 18; e += 256) {
        int ci = e / 324; int rem = e - ci * 324; int yy = rem / 18; int xx = rem - yy * 18;
        int gy = ty0 + yy - 1, gx = tx0 + xx - 1;
        float v = 0.0f;
        if (gy >= 0 && gy < 128 && gx >= 0 && gx < 128)
            v = sim[((long)n * 8 + ci) * HW + gy * 128 + gx];
        ls[ci][yy][xx] = v;
    }
    __syncthreads();
    int yy = t >> 4, xx = t & 15;
    float acc[32] = {};
#pragma unroll
    for (int ci = 0; ci < 8; ++ci)
#pragma unroll
        for (int dy = 0; dy < 3; ++dy)
#pragma unroll
            for (int dx = 0; dx < 3; ++dx) {
                float v = ls[ci][yy + dy][xx + dx];
                const float* wp = &lw[ci * 288 + (dy * 3 + dx) * 32];
#pragma unroll
                for (int o = 0; o < 32; o += 4) {
                    float4 w = *(const float4*)&wp[o];
                    acc[o]     = fmaf(v, w.x, acc[o]);
                    acc[o + 1] = fmaf(v, w.y, acc[o + 1]);
                    acc[o + 2] = fmaf(v, w.z, acc[o + 2]);
                    acc[o + 3] = fmaf(v, w.w, acc[o + 3]);
                }
            }
    long obase = (long)n * 32 * HW + (ty0 + yy) * 128 + tx0 + xx;
    for (int o = 0; o < 32; ++o)
        fdir[obase + (long)o * HW] = acc[o] + b_dir[o];
}

// ---------------------------------------------------------------- fdist weight prep: fragment-ordered bf16
__global__ __launch_bounds__(256) void k_wprep(const float* __restrict__ w,
                                               unsigned short* __restrict__ wf) {
    int t = blockIdx.x * 256 + threadIdx.x;   // 4608 total
    if (t >= 4608) return;
    int lane = t & 63;
    int mt = (t >> 6) & 1;
    int tap = (t >> 7) % 9;
    int c = t / 1152;
    int o = mt * 16 + (lane & 15);
    int cib = c * 32 + (lane >> 4) * 8;
    short8 sv;
#pragma unroll
    for (int j = 0; j < 8; ++j)
        sv[j] = (short)f2bf(w[(long)o * 1152 + (cib + j) * 9 + tap]);
    *(short8*)&wf[(long)t * 8] = sv;
}

// ---------------------------------------------------------------- fdist: 3x3 conv |cp1-sp1| 128->32 via MFMA
__global__ __launch_bounds__(512) void k_fdist(const unsigned short* __restrict__ cp1,
                                               const unsigned short* __restrict__ sp1,
                                               const unsigned short* __restrict__ wf,
                                               const float* __restrict__ b_dist,
                                               float* __restrict__ fdb) {
    __shared__ unsigned short Bs[32 * 912];   // 58,368 B
    int t = threadIdx.x;
    int lane = t & 63, wv = t >> 6;
    int l15 = lane & 15, quad = lane >> 4;
    int bid = blockIdx.x;
    int n = bid >> 5;
    int row0 = (bid & 31) * 4;

    // zero x-halo columns (cols 7 and 136 of each (kp,row) plane) -- stay zero all chunks
    for (int e = t; e < 384; e += 512) {
        int kp = e / 12, rem = e % 12, row = rem >> 1;
        Bs[kp * 912 + row * 144 + ((rem & 1) ? 136 : 7)] = 0;
    }

    f32x4 acc[2][4];
#pragma unroll
    for (int mt = 0; mt < 2; ++mt)
#pragma unroll
        for (int nt = 0; nt < 4; ++nt) acc[mt][nt] = (f32x4){0.f, 0.f, 0.f, 0.f};

    for (int c = 0; c < 4; ++c) {
        if (c) __syncthreads();            // previous compute done reading Bs
        // ---- stage |cp1-sp1| chunk (32 ch x 6 rows x 128 x) as bf16
#pragma unroll
        for (int i = 0; i < 6; ++i) {
            int e = i * 512 + t;           // 3072 units of 8 x-pixels
            int k = e / 96;
            int rem = e - k * 96;
            int row = rem >> 4, col8 = rem & 15;
            int gy = row0 + row - 1;
            short8 dv = (short8){0, 0, 0, 0, 0, 0, 0, 0};
            if (gy >= 0 && gy < 128) {
                long gidx = ((long)(n * 128 + c * 32 + k)) * HW + gy * 128 + col8 * 8;
                short8 a = *(const short8*)(cp1 + gidx);
                short8 b = *(const short8*)(sp1 + gidx);
#pragma unroll
                for (int j = 0; j < 8; ++j)
                    dv[j] = (short)f2bf(fabsf(bf2f((unsigned short)a[j]) -
                                              bf2f((unsigned short)b[j])));
            }
            *(short8*)&Bs[((k & 7) * 4 + (k >> 3)) * 912 + row * 144 + 8 + col8 * 8] = dv;
        }
        __syncthreads();
        // ---- A fragments for this chunk: 9 taps x 2 mt, single b128 global load each (L2-hot)
        short8 af[9][2];
        const short8* wp = ((const short8*)wf) + (long)c * 1152 + lane;
#pragma unroll
        for (int tap = 0; tap < 9; ++tap)
#pragma unroll
            for (int mt = 0; mt < 2; ++mt)
                af[tap][mt] = wp[(tap * 2 + mt) * 64];
        // ---- MFMA over 9 taps
#pragma unroll
        for (int tap = 0; tap < 9; ++tap) {
            int dy = tap / 3, dx = tap % 3;
#pragma unroll
            for (int nt = 0; nt < 4; ++nt) {
                int tp = wv * 64 + nt * 16 + l15;
                int ba = quad * 912 + ((tp >> 7) + dy) * 144 + (tp & 127) + dx + 7;
                short8 bfr;
#pragma unroll
                for (int j = 0; j < 8; ++j)
                    bfr[j] = (short)Bs[ba + j * 3648];   // j*4 planes * 912
                acc[0][nt] = __builtin_amdgcn_mfma_f32_16x16x32_bf16(
                    af[tap][0], bfr, acc[0][nt], 0, 0, 0);
                acc[1][nt] = __builtin_amdgcn_mfma_f32_16x16x32_bf16(
                    af[tap][1], bfr, acc[1][nt], 0, 0, 0);
            }
        }
    }
    // ---- epilogue: c_out = mt*16 + quad*4 + reg; pixel = wv*64 + nt*16 + l15
#pragma unroll
    for (int mt = 0; mt < 2; ++mt)
#pragma unroll
        for (int reg = 0; reg < 4; ++reg) {
            int co = mt * 16 + quad * 4 + reg;
            float bb = b_dist[co];
            long ob = ((long)n * 32 + co) * HW + row0 * 128;
#pragma unroll
            for (int nt = 0; nt < 4; ++nt) {
                int tp = wv * 64 + nt * 16 + l15;
                fdb[ob + tp] = acc[mt][nt][reg] + bb;
            }
        }
}

// ---------------------------------------------------------------- off: 1x1 conv 192->32
__global__ __launch_bounds__(256) void k_off(const unsigned short* __restrict__ redim,
                                             const float* __restrict__ fdir,
                                             const float* __restrict__ fdb,
                                             const float* __restrict__ w_off,
                                             const float* __restrict__ b_off,
                                             float* __restrict__ off) {
    __shared__ float lw[192 * 32];
    int t = threadIdx.x;
    int bid = blockIdx.x;    // 8 * 64
    int n = bid >> 6;
    int p0 = (bid & 63) * 256;
    for (int e = t; e < 6144; e += 256) {
        int co = e & 31; int k = e >> 5;
        lw[k * 32 + co] = w_off[co * 192 + k];
    }
    __syncthreads();
    int p = p0 + t;
    float acc[32] = {};
    for (int k = 0; k < 192; ++k) {
        float v;
        if (k < 128)      v = bf2f(redim[((long)n * 128 + k) * HW + p]);
        else if (k < 160) v = fdir[((long)n * 32 + (k - 128)) * HW + p];
        else              v = fdb[((long)n * 32 + (k - 160)) * HW + p];
        const float* wp = &lw[k * 32];
#pragma unroll
        for (int o = 0; o < 32; o += 4) {
            float4 w = *(const float4*)&wp[o];
            acc[o]     = fmaf(v, w.x, acc[o]);
            acc[o + 1] = fmaf(v, w.y, acc[o + 1]);
            acc[o + 2] = fmaf(v, w.z, acc[o + 2]);
            acc[o + 3] = fmaf(v, w.w, acc[o + 3]);
        }
    }
    for (int o = 0; o < 32; ++o)
        off[((long)n * 32 + o) * HW + p] = acc[o] + b_off[o];
}

// ---------------------------------------------------------------- gsample metadata prep
// per (n,gg,pixel): packed corner offsets + fp16 weight factors for both samples.
__device__ __forceinline__ void gs_meta(float gx, float gy,
                                        unsigned int& pk, unsigned int& hab,
                                        unsigned int& hcd) {
    float x0f = floorf(gx), y0f = floorf(gy);
    float wx = gx - x0f, wy = gy - y0f;
    int x0 = (int)x0f, y0 = (int)y0f;
    float vx0 = (x0 >= 0 && x0 <= 127) ? 1.f : 0.f;
    float vx1 = (x0 + 1 >= 0 && x0 + 1 <= 127) ? 1.f : 0.f;
    float vy0 = (y0 >= 0 && y0 <= 127) ? 1.f : 0.f;
    float vy1 = (y0 + 1 >= 0 && y0 + 1 <= 127) ? 1.f : 0.f;
    int x0c = min(max(x0, 0), 127), x1c = min(max(x0 + 1, 0), 127);
    int y0c = min(max(y0, 0), 127), y1c = min(max(y0 + 1, 0), 127);
    unsigned int o00 = (unsigned int)(y0c * 128 + x0c);
    unsigned int dx = (unsigned int)(x1c - x0c), dy = (unsigned int)(y1c - y0c);
    pk = o00 | (dx << 14) | (dy << 15);
    __half2 ab = __floats2half2_rn((1.f - wx) * vx0, wx * vx1);
    __half2 cd = __floats2half2_rn((1.f - wy) * vy0, wy * vy1);
    hab = *(unsigned int*)&ab;
    hcd = *(unsigned int*)&cd;
}

__global__ __launch_bounds__(256) void k_gprep(const float* __restrict__ off,
                                               unsigned int* __restrict__ pofs,
                                               uint4* __restrict__ phw) {
    int idx = blockIdx.x * 256 + threadIdx.x;  // 64 * 16384
    int p = idx & 16383;
    int ng = idx >> 14;
    int n = ng >> 3, gg = ng & 7;
    int x = p & 127, y = p >> 7;
    const float* ob = off + (long)n * 32 * HW + p;
    float lx = ob[(long)(2 * gg) * HW];
    float ly = ob[(long)(2 * gg + 1) * HW];
    float hx = ob[(long)(16 + 2 * gg) * HW];
    float hy = ob[(long)(17 + 2 * gg) * HW];
    const float C = 127.0f / 256.0f;
    unsigned int pkc, cab, ccd, pks, sab, scd;
    gs_meta((float)x + lx * C, (float)y + ly * C, pkc, cab, ccd);
    gs_meta((float)x + hx * C, (float)y + hy * C, pks, sab, scd);
    pofs[idx] = pkc | (pks << 16);
    phw[idx] = make_uint4(cab, ccd, sab, scd);
}

// ---------------------------------------------------------------- grid sample + add
// cp plane fp32 in LDS (64 KB, round-4 proven), spu plane bf16 copy (32 KB,
// no conversion VALU since spu is stored bf16). 96 KB/block.
__device__ __forceinline__ float2 h2f2(unsigned int u) {
    __half2 h = *(__half2*)&u;
    return __half22float2(h);
}

__global__ __launch_bounds__(1024) void k_gsample(const float* __restrict__ cp,
                                                  const unsigned short* __restrict__ spu,
                                                  const unsigned int* __restrict__ pofs,
                                                  const uint4* __restrict__ phw,
                                                  float* __restrict__ out) {
    __shared__ float lc[16384];            // cp plane fp32 (64 KB)
    __shared__ unsigned short lsp[16384];  // spu plane bf16 (32 KB)
    int t = threadIdx.x;
    // XCD-aware bijective swizzle: 2048 blocks = 8 XCD * 256; blocks sharing
    // (n,gg) land on the same XCD -> prep slice stays L2-resident.
    int bid = (blockIdx.x & 7) * 256 + (blockIdx.x >> 3);
    int n = bid >> 8;
    int gg = (bid >> 5) & 7;
    int ci = bid & 31;
    long plane = ((long)n * 256 + gg * 32 + ci) * (long)HW;
    const float* pc = cp + plane;
    const unsigned short* ps = spu + plane;
    // ---- stage cp plane fp32 (float4) + spu plane bf16 (uint4 raw copy)
#pragma unroll
    for (int i = 0; i < 4; ++i) {
        int idx = (i * 1024 + t) * 4;
        *(float4*)&lc[idx] = *(const float4*)&pc[idx];
    }
#pragma unroll
    for (int i = 0; i < 2; ++i) {
        int idx = (i * 1024 + t) * 8;
        *(uint4*)&lsp[idx] = *(const uint4*)&ps[idx];
    }
    // ---- prefetch packed offsets (independent of LDS; in flight over the barrier)
    long base = ((long)n * 8 + gg) * (long)HW;
    unsigned int pks[16];
#pragma unroll
    for (int it = 0; it < 16; ++it) pks[it] = pofs[base + it * 1024 + t];
    __syncthreads();
    // ---- gather from LDS, 16 pixels/thread
    float* op = out + plane;
#pragma unroll
    for (int it = 0; it < 16; ++it) {
        int p = it * 1024 + t;
        unsigned int pk = pks[it];
        uint4 hw = phw[base + p];
        // cs (fp32 plane)
        unsigned int oc = pk & 0x3FFFu;
        unsigned int dxc = (pk >> 14) & 1u, dyc = (pk >> 15) & 1u;
        float2 ab = h2f2(hw.x), cd = h2f2(hw.y);
        unsigned int oc1 = oc + (dyc << 7);
        float r = lc[oc] * (ab.x * cd.x) + lc[oc + dxc] * (ab.y * cd.x) +
                  lc[oc1] * (ab.x * cd.y) + lc[oc1 + dxc] * (ab.y * cd.y);
        // ss (bf16 plane)
        unsigned int os = (pk >> 16) & 0x3FFFu;
        unsigned int dxs = (pk >> 30) & 1u, dys = pk >> 31;
        float2 ab2 = h2f2(hw.z), cd2 = h2f2(hw.w);
        unsigned int os1 = os + (dys << 7);
        r += bf2f(lsp[os]) * (ab2.x * cd2.x) + bf2f(lsp[os + dxs]) * (ab2.y * cd2.x) +
             bf2f(lsp[os1]) * (ab2.x * cd2.y) + bf2f(lsp[os1 + dxs]) * (ab2.y * cd2.y);
        op[p] = r;
    }
}

// ---------------------------------------------------------------- launch
extern "C" void kernel_launch(void* const* d_in, const int* in_sizes, int n_in,
                              void* d_out, int out_size, void* d_ws, size_t ws_size,
                              hipStream_t stream) {
    const float* cp      = (const float*)d_in[0];
    const float* sp      = (const float*)d_in[1];
    const float* w_cp    = (const float*)d_in[2];
    const float* g_cp    = (const float*)d_in[3];
    const float* b_cp    = (const float*)d_in[4];
    const float* w_sp    = (const float*)d_in[5];
    const float* g_sp    = (const float*)d_in[6];
    const float* b_sp    = (const float*)d_in[7];
    const float* w_redim = (const float*)d_in[8];
    const float* b_redim = (const float*)d_in[9];
    const float* w_dir   = (const float*)d_in[10];
    const float* b_dir   = (const float*)d_in[11];
    const float* w_dist  = (const float*)d_in[12];
    const float* b_dist  = (const float*)d_in[13];
    const float* w_off   = (const float*)d_in[14];
    const float* b_off   = (const float*)d_in[15];
    float* out = (float*)d_out;

    char* ws = (char*)d_ws;
    size_t o = 0;
    unsigned short* spub  = (unsigned short*)(ws + o); o += 8L * 256 * HW * 2;   // 67 MB bf16
    unsigned short* cp1b  = (unsigned short*)(ws + o); o += 8L * 128 * HW * 2;   // 33.5 MB
    unsigned short* sp1b  = (unsigned short*)(ws + o); o += 8L * 128 * HW * 2;
    unsigned short* redb  = (unsigned short*)(ws + o); o += 8L * 128 * HW * 2;
    float* simb           = (float*)(ws + o);          o += 8L * 8 * HW * 4;
    float* fdirb          = (float*)(ws + o);          o += 8L * 32 * HW * 4;
    float* fdb            = (float*)(ws + o);          o += 8L * 32 * HW * 4;    // single full-K buffer
    float* offb           = (float*)(ws + o);          o += 8L * 32 * HW * 4;
    unsigned short* wfb   = (unsigned short*)(ws + o); o += 4608L * 8 * 2;       // 73,728 B
    unsigned int* pofsb   = (unsigned int*)(ws + o);   o += 64L * HW * 4;        // 4.2 MB
    uint4* phwb           = (uint4*)(ws + o);          o += 64L * HW * 16;       // 16.8 MB

    if (ws_size < o) {
        k_sentinel<<<(out_size + 255) / 256, 256, 0, stream>>>(
            out, (float)(ws_size >> 20), out_size);
        return;
    }

    k_upsample<<<65536, 256, 0, stream>>>(sp, spub);
    k_wprep<<<18, 256, 0, stream>>>(w_dist, wfb);
    k_mgemm<0><<<1024, 256, 0, stream>>>(cp, cp + 128L * HW, 256L * HW, 256L * HW,
                                         w_cp, g_cp, b_cp, cp1b, 1);
    k_mgemm<1><<<1024, 256, 0, stream>>>(spub, spub + 128L * HW, 256L * HW, 256L * HW,
                                         w_sp, g_sp, b_sp, sp1b, 1);
    k_mgemm<1><<<1024, 256, 0, stream>>>(cp1b, sp1b, 128L * HW, 128L * HW,
                                         w_redim, nullptr, b_redim, redb, 0);
    k_sim<<<4096, 256, 0, stream>>>(cp1b, sp1b, simb);
    k_fdir<<<512, 256, 0, stream>>>(simb, w_dir, b_dir, fdirb);
    k_fdist<<<256, 512, 0, stream>>>(cp1b, sp1b, wfb, b_dist, fdb);
    k_off<<<512, 256, 0, stream>>>(redb, fdirb, fdb, w_off, b_off, offb);
    k_gprep<<<4096, 256, 0, stream>>>(offb, pofsb, phwb);
    k_gsample<<<2048, 1024, 0, stream>>>(cp, spub, pofsb, phwb, out);
}